// Round 1
// baseline (50.454 us; speedup 1.0000x reference)
//
#include <hip/hip_runtime.h>

// PolyAttn collapse: a = s^4/|s^4| == 1.0 identically, so
//   out[b,n,:] = (sum_m v[b,m,:]) @ w_o   (independent of n, q, k, alpha)
//   with v[b,m,:] = x[b,m,:] @ w_qkv[:, 2H:3H]
// and reductions commute: vsum[b,:] = (sum_n x[b,n,:]) @ w_v.

#define B_ 4
#define N_ 2048
#define D_ 1024
#define H_ 1024
#define H3_ 3072

// ---- kernel 1: xsum[b,d] = sum_n x[b,n,d] ----------------------------------
// grid (B, 64) x 256 threads; each block reduces 32 rows, float4 per thread.
__global__ void k_xsum(const float* __restrict__ x, float* __restrict__ xsum) {
    const int b  = blockIdx.x;
    const int n0 = blockIdx.y * 32;
    const int t  = threadIdx.x;            // 0..255, covers D/4 float4s
    const float4* x4 = reinterpret_cast<const float4*>(x);
    // float4 index of (b, n0, 4t)
    size_t base = ((size_t)b * N_ + n0) * (D_ / 4) + t;
    float4 acc = make_float4(0.f, 0.f, 0.f, 0.f);
#pragma unroll 8
    for (int i = 0; i < 32; ++i) {
        float4 v = x4[base + (size_t)i * (D_ / 4)];
        acc.x += v.x; acc.y += v.y; acc.z += v.z; acc.w += v.w;
    }
    float* dst = xsum + b * D_ + 4 * t;
    atomicAdd(dst + 0, acc.x);
    atomicAdd(dst + 1, acc.y);
    atomicAdd(dst + 2, acc.z);
    atomicAdd(dst + 3, acc.w);
}

// ---- kernel 2: vsum[b,h] = sum_d xsum[b,d] * w_qkv[d, 2H+h] ----------------
// grid (H/256, 8) x 256; each block does a 128-wide d-chunk for all 4 b.
__global__ void k_vsum(const float* __restrict__ xsum,
                       const float* __restrict__ w_qkv,
                       float* __restrict__ vsum) {
    const int h  = blockIdx.x * 256 + threadIdx.x;
    const int d0 = blockIdx.y * 128;
    float acc0 = 0.f, acc1 = 0.f, acc2 = 0.f, acc3 = 0.f;
    for (int i = 0; i < 128; ++i) {
        const int d = d0 + i;
        const float w = w_qkv[(size_t)d * H3_ + 2 * H_ + h];  // coalesced in h
        acc0 += xsum[0 * D_ + d] * w;
        acc1 += xsum[1 * D_ + d] * w;
        acc2 += xsum[2 * D_ + d] * w;
        acc3 += xsum[3 * D_ + d] * w;
    }
    atomicAdd(&vsum[0 * H_ + h], acc0);
    atomicAdd(&vsum[1 * H_ + h], acc1);
    atomicAdd(&vsum[2 * H_ + h], acc2);
    atomicAdd(&vsum[3 * H_ + h], acc3);
}

// ---- kernel 3: orow[b,d] = sum_h vsum[b,h] * w_o[h,d] ----------------------
// grid (D/256, 8) x 256; each block does a 128-wide h-chunk for all 4 b.
__global__ void k_orow(const float* __restrict__ vsum,
                       const float* __restrict__ w_o,
                       float* __restrict__ orow) {
    const int d  = blockIdx.x * 256 + threadIdx.x;
    const int h0 = blockIdx.y * 128;
    float acc0 = 0.f, acc1 = 0.f, acc2 = 0.f, acc3 = 0.f;
    for (int i = 0; i < 128; ++i) {
        const int h = h0 + i;
        const float w = w_o[(size_t)h * D_ + d];              // coalesced in d
        acc0 += vsum[0 * H_ + h] * w;
        acc1 += vsum[1 * H_ + h] * w;
        acc2 += vsum[2 * H_ + h] * w;
        acc3 += vsum[3 * H_ + h] * w;
    }
    atomicAdd(&orow[0 * D_ + d], acc0);
    atomicAdd(&orow[1 * D_ + d], acc1);
    atomicAdd(&orow[2 * D_ + d], acc2);
    atomicAdd(&orow[3 * D_ + d], acc3);
}

// ---- kernel 4: out[b,n,:] = orow[b,:] broadcast over n ---------------------
__global__ void k_bcast(const float* __restrict__ orow, float* __restrict__ out) {
    const size_t total4 = (size_t)B_ * N_ * (D_ / 4);   // 2,097,152 float4s
    const float4* o4 = reinterpret_cast<const float4*>(orow);
    float4* out4 = reinterpret_cast<float4*>(out);
    for (size_t i = (size_t)blockIdx.x * blockDim.x + threadIdx.x; i < total4;
         i += (size_t)gridDim.x * blockDim.x) {
        const int d4 = (int)(i & (D_ / 4 - 1));     // i % 256
        const int bn = (int)(i >> 8);               // / 256
        const int b  = bn >> 11;                    // / 2048
        out4[i] = o4[b * (D_ / 4) + d4];
    }
}

extern "C" void kernel_launch(void* const* d_in, const int* in_sizes, int n_in,
                              void* d_out, int out_size, void* d_ws, size_t ws_size,
                              hipStream_t stream) {
    const float* x     = (const float*)d_in[0];   // [B, N, D]
    const float* w_qkv = (const float*)d_in[1];   // [D, 3H]
    const float* w_o   = (const float*)d_in[2];   // [H, D]
    // d_in[3] = alpha — provably unused (a == 1 regardless of alpha).
    float* out = (float*)d_out;                   // [B, N, D] fp32

    float* xsum = (float*)d_ws;                   // B*D   = 4096 floats
    float* vsum = xsum + B_ * D_;                 // B*H   = 4096 floats
    float* orow = vsum + B_ * H_;                 // B*D   = 4096 floats

    hipMemsetAsync(d_ws, 0, (size_t)3 * B_ * D_ * sizeof(float), stream);

    k_xsum<<<dim3(B_, 64), 256, 0, stream>>>(x, xsum);
    k_vsum<<<dim3(H_ / 256, 8), 256, 0, stream>>>(xsum, w_qkv, vsum);
    k_orow<<<dim3(D_ / 256, 8), 256, 0, stream>>>(vsum, w_o, orow);
    k_bcast<<<2048, 256, 0, stream>>>(orow, out);
}

// Round 2
// 37.604 us; speedup vs baseline: 1.3417x; 1.3417x over previous
//
#include <hip/hip_runtime.h>

// PolyAttn collapse: a = s^4/|s^4| == 1.0 identically, so
//   out[b,n,:] = (sum_m v[b,m,:]) @ w_o   (independent of n, q, k, alpha)
//   with vsum[b,:] = (sum_n x[b,n,:]) @ w_qkv[:, 2H:3H].
// No memset in the graph: k_xsum writes per-block partials (no atomics),
// k_xsum_reduce folds them and zeroes the two atomic targets itself.

#define B_ 4
#define N_ 2048
#define D_ 1024
#define H_ 1024
#define H3_ 3072
#define NGRP_ 64          // partial-sum groups per batch (32 rows each)

// ---- kernel 1: partial[b][g][d] = sum over 32 rows of x ---------------------
// grid (B, NGRP) x 256 threads; float4 per thread; plain stores.
__global__ void k_xsum(const float* __restrict__ x, float4* __restrict__ part4) {
    const int b  = blockIdx.x;
    const int g  = blockIdx.y;
    const int t  = threadIdx.x;            // 0..255 -> float4 slot in D
    const float4* x4 = reinterpret_cast<const float4*>(x);
    size_t base = ((size_t)b * N_ + g * 32) * (D_ / 4) + t;
    float4 acc = make_float4(0.f, 0.f, 0.f, 0.f);
#pragma unroll 8
    for (int i = 0; i < 32; ++i) {
        float4 v = x4[base + (size_t)i * (D_ / 4)];
        acc.x += v.x; acc.y += v.y; acc.z += v.z; acc.w += v.w;
    }
    part4[((size_t)b * NGRP_ + g) * (D_ / 4) + t] = acc;
}

// ---- kernel 2: xsum[b][d] = sum_g part[b][g][d]; also zero vsum & orow ------
// grid 4 x 256 = 1024 threads; one float4 column each.
__global__ void k_xsum_reduce(const float4* __restrict__ part4,
                              float4* __restrict__ xsum4,
                              float4* __restrict__ vsum4,
                              float4* __restrict__ orow4) {
    const int i  = blockIdx.x * 256 + threadIdx.x;   // 0..1023
    const int b  = i >> 8;                           // / 256
    const int d4 = i & 255;
    const float4* p = part4 + (size_t)b * NGRP_ * 256 + d4;
    float4 acc = make_float4(0.f, 0.f, 0.f, 0.f);
#pragma unroll 8
    for (int g = 0; g < NGRP_; ++g) {
        float4 v = p[(size_t)g * 256];
        acc.x += v.x; acc.y += v.y; acc.z += v.z; acc.w += v.w;
    }
    xsum4[i] = acc;
    vsum4[i] = make_float4(0.f, 0.f, 0.f, 0.f);
    orow4[i] = make_float4(0.f, 0.f, 0.f, 0.f);
}

// ---- kernel 3: vsum[b,h] += sum_{d in chunk} xsum[b,d] * w_qkv[d, 2H+h] ----
// grid (H/256, 16) x 256; each block covers a 64-wide d-chunk, all 4 b.
__global__ void k_vsum(const float* __restrict__ xsum,
                       const float* __restrict__ w_qkv,
                       float* __restrict__ vsum) {
    const int h  = blockIdx.x * 256 + threadIdx.x;
    const int d0 = blockIdx.y * 64;
    float acc0 = 0.f, acc1 = 0.f, acc2 = 0.f, acc3 = 0.f;
#pragma unroll 4
    for (int i = 0; i < 64; ++i) {
        const int d = d0 + i;
        const float w = w_qkv[(size_t)d * H3_ + 2 * H_ + h];  // coalesced in h
        acc0 += xsum[0 * D_ + d] * w;
        acc1 += xsum[1 * D_ + d] * w;
        acc2 += xsum[2 * D_ + d] * w;
        acc3 += xsum[3 * D_ + d] * w;
    }
    atomicAdd(&vsum[0 * H_ + h], acc0);
    atomicAdd(&vsum[1 * H_ + h], acc1);
    atomicAdd(&vsum[2 * H_ + h], acc2);
    atomicAdd(&vsum[3 * H_ + h], acc3);
}

// ---- kernel 4: orow[b,d] += sum_{h in chunk} vsum[b,h] * w_o[h,d] ----------
__global__ void k_orow(const float* __restrict__ vsum,
                       const float* __restrict__ w_o,
                       float* __restrict__ orow) {
    const int d  = blockIdx.x * 256 + threadIdx.x;
    const int h0 = blockIdx.y * 64;
    float acc0 = 0.f, acc1 = 0.f, acc2 = 0.f, acc3 = 0.f;
#pragma unroll 4
    for (int i = 0; i < 64; ++i) {
        const int h = h0 + i;
        const float w = w_o[(size_t)h * D_ + d];              // coalesced in d
        acc0 += vsum[0 * H_ + h] * w;
        acc1 += vsum[1 * H_ + h] * w;
        acc2 += vsum[2 * H_ + h] * w;
        acc3 += vsum[3 * H_ + h] * w;
    }
    atomicAdd(&orow[0 * D_ + d], acc0);
    atomicAdd(&orow[1 * D_ + d], acc1);
    atomicAdd(&orow[2 * D_ + d], acc2);
    atomicAdd(&orow[3 * D_ + d], acc3);
}

// ---- kernel 5: out[b,n,:] = orow[b,:] broadcast over n ---------------------
__global__ void k_bcast(const float* __restrict__ orow, float* __restrict__ out) {
    const size_t total4 = (size_t)B_ * N_ * (D_ / 4);   // 2,097,152 float4s
    const float4* o4 = reinterpret_cast<const float4*>(orow);
    float4* out4 = reinterpret_cast<float4*>(out);
    for (size_t i = (size_t)blockIdx.x * blockDim.x + threadIdx.x; i < total4;
         i += (size_t)gridDim.x * blockDim.x) {
        const int d4 = (int)(i & (D_ / 4 - 1));     // i % 256
        const int bn = (int)(i >> 8);               // / 256
        const int b  = bn >> 11;                    // / 2048
        out4[i] = o4[b * (D_ / 4) + d4];
    }
}

extern "C" void kernel_launch(void* const* d_in, const int* in_sizes, int n_in,
                              void* d_out, int out_size, void* d_ws, size_t ws_size,
                              hipStream_t stream) {
    const float* x     = (const float*)d_in[0];   // [B, N, D]
    const float* w_qkv = (const float*)d_in[1];   // [D, 3H]
    const float* w_o   = (const float*)d_in[2];   // [H, D]
    // d_in[3] = alpha — provably unused (a == 1 regardless of alpha).
    float* out = (float*)d_out;                   // [B, N, D] fp32

    float* part = (float*)d_ws;                           // B*NGRP*D = 262144 floats (1 MB)
    float* xsum = part + (size_t)B_ * NGRP_ * D_;         // B*D = 4096 floats
    float* vsum = xsum + B_ * D_;                         // B*H = 4096 floats
    float* orow = vsum + B_ * H_;                         // B*D = 4096 floats

    k_xsum<<<dim3(B_, NGRP_), 256, 0, stream>>>(x, (float4*)part);
    k_xsum_reduce<<<4, 256, 0, stream>>>((const float4*)part, (float4*)xsum,
                                         (float4*)vsum, (float4*)orow);
    k_vsum<<<dim3(H_ / 256, 16), 256, 0, stream>>>(xsum, w_qkv, vsum);
    k_orow<<<dim3(D_ / 256, 16), 256, 0, stream>>>(vsum, w_o, orow);
    k_bcast<<<2048, 256, 0, stream>>>(orow, out);
}